// Round 3
// baseline (2891.937 us; speedup 1.0000x reference)
//
#include <hip/hip_runtime.h>

// Problem constants: B=16, C=64, H=128, W=128, bchw layout, HW = 16384
// Output: fp32 (reference returns float32). Q/K/V staged as bf16 in ws.
#define HW 16384
#define NE 16777216ull   // B*C*H*W

__device__ __forceinline__ unsigned short f2bf(float f) {
    unsigned int u = __float_as_uint(f);
    unsigned int r = (u + 0x7FFFu + ((u >> 16) & 1u)) >> 16;  // RNE
    return (unsigned short)r;
}
__device__ __forceinline__ float bf2f(unsigned short s) {
    return __uint_as_float(((unsigned int)s) << 16);
}

__global__ __launch_bounds__(128)
void zero_stats_kernel(float* __restrict__ stats) {
    stats[threadIdx.x] = 0.f;
}

// out[b,o,hw] = bf16( sum_c w[o,c] * in[b,c,hw] + bias[o] )
// block: 256 threads = 8 o-groups x 32 pixel-lanes; 256 pixels/block.
__global__ __launch_bounds__(256)
void proj_kernel(const float* __restrict__ in, const float* __restrict__ w,
                 const float* __restrict__ bias, unsigned short* __restrict__ out) {
    __shared__ float swT[64 * 64];  // swT[c*64+o] = w[o*64+c]
    int tid = threadIdx.x;
    for (int i = tid; i < 4096; i += 256) {
        int o = i >> 6, c = i & 63;
        swT[c * 64 + o] = w[i];
    }
    __syncthreads();
    int ty = tid >> 5;            // 0..7 -> outputs ty*8..ty*8+7
    int tx = tid & 31;            // pixel lane
    int pbase = blockIdx.x * 256;
    int b = pbase >> 14;
    int hw0 = (pbase & 16383) + tx;
    const float* inb = in + (size_t)b * (64 * HW);
    float acc[8][8];
#pragma unroll
    for (int j = 0; j < 8; ++j) {
        float bj = bias[ty * 8 + j];
#pragma unroll
        for (int i = 0; i < 8; ++i) acc[j][i] = bj;
    }
    for (int c = 0; c < 64; ++c) {
        float xv[8];
#pragma unroll
        for (int i = 0; i < 8; ++i) xv[i] = inb[c * HW + hw0 + i * 32];
        float4 w0 = *(const float4*)&swT[c * 64 + ty * 8];
        float4 w1 = *(const float4*)&swT[c * 64 + ty * 8 + 4];
        float wv[8] = {w0.x, w0.y, w0.z, w0.w, w1.x, w1.y, w1.z, w1.w};
#pragma unroll
        for (int j = 0; j < 8; ++j)
#pragma unroll
            for (int i = 0; i < 8; ++i) acc[j][i] += wv[j] * xv[i];
    }
    unsigned short* outb = out + (size_t)b * (64 * HW);
#pragma unroll
    for (int j = 0; j < 8; ++j)
#pragma unroll
        for (int i = 0; i < 8; ++i)
            outb[(ty * 8 + j) * HW + hw0 + i * 32] = f2bf(acc[j][i]);
}

// One block per (b,c): csi = softmax(Q K^T / sqrt(128)) V   (Q/K/V bf16, math fp32)
// accumulate=0: io (fp32) = csi
// accumulate=1: io += csi; accumulate BN sum/sumsq from stored fp32 value.
// LDS: phase A: Q-tile 128x33 + K-tile 128x33; phase B (aliased): P 128x33 + V 32x132.
__global__ __launch_bounds__(512)
void attn_kernel(const unsigned short* __restrict__ Q, const unsigned short* __restrict__ K,
                 const unsigned short* __restrict__ V, float* __restrict__ io,
                 float* __restrict__ stats, int accumulate) {
    __shared__ float lds[8448];
    __shared__ float redA[8], redB[8];
    float* ldsQ = lds;          // 128 x 33 (phase A) ; P (phase B)
    float* ldsK = lds + 4224;   // 128 x 33 (phase A) ; V 32 x 132 (phase B)

    int bc = blockIdx.x;
    size_t base = (size_t)bc * HW;
    int tid = threadIdx.x;
    int ty = tid >> 4;   // 0..31 -> rows ty*4 .. ty*4+3
    int tx = tid & 15;   // cols tx*8 .. tx*8+7

    // ---- Phase A: S = Q K^T (registers), chunked over w ----
    float s[4][8];
#pragma unroll
    for (int i = 0; i < 4; ++i)
#pragma unroll
        for (int j = 0; j < 8; ++j) s[i][j] = 0.f;

    for (int ch = 0; ch < 4; ++ch) {
        int w0 = ch * 32;
        __syncthreads();
        for (int i = tid; i < 4096; i += 512) {
            int r = i >> 5, w = i & 31;
            ldsQ[r * 33 + w] = bf2f(Q[base + r * 128 + w0 + w]);
        }
        for (int i = tid; i < 4096; i += 512) {
            int r = i >> 5, w = i & 31;
            ldsK[r * 33 + w] = bf2f(K[base + r * 128 + w0 + w]);
        }
        __syncthreads();
        for (int kk = 0; kk < 32; ++kk) {
            float qv[4], kv[8];
#pragma unroll
            for (int i = 0; i < 4; ++i) qv[i] = ldsQ[(ty * 4 + i) * 33 + kk];
#pragma unroll
            for (int j = 0; j < 8; ++j) kv[j] = ldsK[(tx * 8 + j) * 33 + kk];
#pragma unroll
            for (int i = 0; i < 4; ++i)
#pragma unroll
                for (int j = 0; j < 8; ++j) s[i][j] += qv[i] * kv[j];
        }
    }

    // ---- Softmax over g (split across 16 tx lanes), in registers ----
    const float scale = 0.08838834764831845f;  // 1/sqrt(128)
    float p[4][8];
#pragma unroll
    for (int i = 0; i < 4; ++i) {
        float m = -3.4e38f;
#pragma unroll
        for (int j = 0; j < 8; ++j) { s[i][j] *= scale; m = fmaxf(m, s[i][j]); }
#pragma unroll
        for (int mask = 8; mask >= 1; mask >>= 1)
            m = fmaxf(m, __shfl_xor(m, mask));
        float l = 0.f;
#pragma unroll
        for (int j = 0; j < 8; ++j) { float e = __expf(s[i][j] - m); p[i][j] = e; l += e; }
#pragma unroll
        for (int mask = 8; mask >= 1; mask >>= 1)
            l += __shfl_xor(l, mask);
        float inv = 1.0f / l;
#pragma unroll
        for (int j = 0; j < 8; ++j) p[i][j] *= inv;
    }

    // ---- Phase B: O = P V, chunked over g (P and V staged in aliased LDS) ----
    float o[4][8];
#pragma unroll
    for (int i = 0; i < 4; ++i)
#pragma unroll
        for (int j = 0; j < 8; ++j) o[i][j] = 0.f;

    for (int q = 0; q < 4; ++q) {
        __syncthreads();  // protects phase-A reads (q==0) / previous chunk reads
        if ((tx >> 2) == q) {
#pragma unroll
            for (int i = 0; i < 4; ++i)
#pragma unroll
                for (int j = 0; j < 8; ++j)
                    ldsQ[(ty * 4 + i) * 33 + (tx & 3) * 8 + j] = p[i][j];
        }
        int g0 = q * 32;
        for (int i2 = tid; i2 < 4096; i2 += 512) {
            int g = i2 >> 7, w = i2 & 127;
            ldsK[g * 132 + w] = bf2f(V[base + (size_t)(g0 + g) * 128 + w]);
        }
        __syncthreads();
        for (int gg = 0; gg < 32; ++gg) {
            float pv[4], vv[8];
#pragma unroll
            for (int i = 0; i < 4; ++i) pv[i] = ldsQ[(ty * 4 + i) * 33 + gg];
#pragma unroll
            for (int j = 0; j < 8; ++j) vv[j] = ldsK[gg * 132 + tx * 8 + j];
#pragma unroll
            for (int i = 0; i < 4; ++i)
#pragma unroll
                for (int j = 0; j < 8; ++j) o[i][j] += pv[i] * vv[j];
        }
    }

    // ---- Epilogue (fp32 io) ----
    if (!accumulate) {
#pragma unroll
        for (int i = 0; i < 4; ++i)
#pragma unroll
            for (int j = 0; j < 8; ++j)
                io[base + (ty * 4 + i) * 128 + tx * 8 + j] = o[i][j];
    } else {
        float lsum = 0.f, lsq = 0.f;
#pragma unroll
        for (int i = 0; i < 4; ++i)
#pragma unroll
            for (int j = 0; j < 8; ++j) {
                size_t idx = base + (ty * 4 + i) * 128 + tx * 8 + j;
                float f = io[idx] + o[i][j];
                io[idx] = f;
                lsum += f;
                lsq += f * f;
            }
#pragma unroll
        for (int mask = 32; mask >= 1; mask >>= 1) {
            lsum += __shfl_xor(lsum, mask);
            lsq  += __shfl_xor(lsq,  mask);
        }
        int wid = tid >> 6;
        if ((tid & 63) == 0) { redA[wid] = lsum; redB[wid] = lsq; }
        __syncthreads();
        if (tid == 0) {
            float a = 0.f, b2 = 0.f;
#pragma unroll
            for (int wv = 0; wv < 8; ++wv) { a += redA[wv]; b2 += redB[wv]; }
            int c = bc & 63;
            atomicAdd(&stats[c], a);
            atomicAdd(&stats[64 + c], b2);
        }
    }
}

// in-place fp32: io = relu((io - mean) * rsqrt(var+eps) * gamma + beta)
__global__ __launch_bounds__(256)
void bn_relu_kernel(float* __restrict__ io, const float* __restrict__ stats,
                    const float* __restrict__ gamma, const float* __restrict__ beta) {
    int idx = blockIdx.x * 256 + threadIdx.x;  // float4 index
    int e = idx << 2;
    int c = (e >> 14) & 63;
    const float invN = 1.0f / 262144.0f;  // B*H*W
    float mean = stats[c] * invN;
    float var = stats[64 + c] * invN - mean * mean;
    float k = rsqrtf(var + 1e-5f) * gamma[c];
    float bb = beta[c] - mean * k;
    float4 f = reinterpret_cast<const float4*>(io)[idx];
    float4 o;
    o.x = fmaxf(f.x * k + bb, 0.f);
    o.y = fmaxf(f.y * k + bb, 0.f);
    o.z = fmaxf(f.z * k + bb, 0.f);
    o.w = fmaxf(f.w * k + bb, 0.f);
    reinterpret_cast<float4*>(io)[idx] = o;
}

extern "C" void kernel_launch(void* const* d_in, const int* in_sizes, int n_in,
                              void* d_out, int out_size, void* d_ws, size_t ws_size,
                              hipStream_t stream) {
    const float* x1 = (const float*)d_in[0];
    const float* x2 = (const float*)d_in[1];
    const float* rssi1 = (const float*)d_in[2];
    const float* rssi2 = (const float*)d_in[3];
    const float* qw = (const float*)d_in[4];
    const float* qb = (const float*)d_in[5];
    const float* kw = (const float*)d_in[6];
    const float* kb = (const float*)d_in[7];
    const float* vw = (const float*)d_in[8];
    const float* vb = (const float*)d_in[9];
    const float* gamma = (const float*)d_in[10];
    const float* beta = (const float*)d_in[11];

    // ws layout: stats first (512 B), then bf16 Q/K/V (32 MB each) = 96 MB + 512 B
    float* stats = (float*)d_ws;
    unsigned short* Q = (unsigned short*)((char*)d_ws + 512);
    unsigned short* K = Q + NE;
    unsigned short* V = K + NE;
    float* io = (float*)d_out;  // fp32 fused / final output, 64 MB

    zero_stats_kernel<<<1, 128, 0, stream>>>(stats);

    dim3 pb(256), pg(1024);

    // branch 1
    proj_kernel<<<pg, pb, 0, stream>>>(rssi1, qw, qb, Q);
    proj_kernel<<<pg, pb, 0, stream>>>(x1, kw, kb, K);
    proj_kernel<<<pg, pb, 0, stream>>>(x1, vw, vb, V);
    attn_kernel<<<1024, 512, 0, stream>>>(Q, K, V, io, stats, 0);

    // branch 2
    proj_kernel<<<pg, pb, 0, stream>>>(rssi2, qw, qb, Q);
    proj_kernel<<<pg, pb, 0, stream>>>(x2, kw, kb, K);
    proj_kernel<<<pg, pb, 0, stream>>>(x2, vw, vb, V);
    attn_kernel<<<1024, 512, 0, stream>>>(Q, K, V, io, stats, 1);

    // BN + ReLU in place on d_out (fp32)
    bn_relu_kernel<<<16384, 256, 0, stream>>>(io, stats, gamma, beta);
}

// Round 4
// 592.128 us; speedup vs baseline: 4.8840x; 4.8840x over previous
//
#include <hip/hip_runtime.h>

// Problem constants: B=16, C=64, H=128, W=128, bchw layout, HW = 16384
// Output: fp32. Q/K/V staged as bf16 in ws. Attention via mfma_f32_16x16x32_bf16.
#define HW 16384
#define NE 16777216ull   // B*C*H*W

typedef short bf16x8 __attribute__((ext_vector_type(8)));
typedef float f32x4  __attribute__((ext_vector_type(4)));

__device__ __forceinline__ unsigned short f2bf(float f) {
    unsigned int u = __float_as_uint(f);
    unsigned int r = (u + 0x7FFFu + ((u >> 16) & 1u)) >> 16;  // RNE
    return (unsigned short)r;
}
__device__ __forceinline__ float bf2f(unsigned short s) {
    return __uint_as_float(((unsigned int)s) << 16);
}

__global__ __launch_bounds__(128)
void zero_stats_kernel(float* __restrict__ stats) {
    stats[threadIdx.x] = 0.f;
}

// out[b,o,hw] = bf16( sum_c w[o,c] * in[b,c,hw] + bias[o] )
__global__ __launch_bounds__(256)
void proj_kernel(const float* __restrict__ in, const float* __restrict__ w,
                 const float* __restrict__ bias, unsigned short* __restrict__ out) {
    __shared__ float swT[64 * 64];  // swT[c*64+o] = w[o*64+c]
    int tid = threadIdx.x;
    for (int i = tid; i < 4096; i += 256) {
        int o = i >> 6, c = i & 63;
        swT[c * 64 + o] = w[i];
    }
    __syncthreads();
    int ty = tid >> 5;
    int tx = tid & 31;
    int pbase = blockIdx.x * 256;
    int b = pbase >> 14;
    int hw0 = (pbase & 16383) + tx;
    const float* inb = in + (size_t)b * (64 * HW);
    float acc[8][8];
#pragma unroll
    for (int j = 0; j < 8; ++j) {
        float bj = bias[ty * 8 + j];
#pragma unroll
        for (int i = 0; i < 8; ++i) acc[j][i] = bj;
    }
    for (int c = 0; c < 64; ++c) {
        float xv[8];
#pragma unroll
        for (int i = 0; i < 8; ++i) xv[i] = inb[c * HW + hw0 + i * 32];
        float4 w0 = *(const float4*)&swT[c * 64 + ty * 8];
        float4 w1 = *(const float4*)&swT[c * 64 + ty * 8 + 4];
        float wv[8] = {w0.x, w0.y, w0.z, w0.w, w1.x, w1.y, w1.z, w1.w};
#pragma unroll
        for (int j = 0; j < 8; ++j)
#pragma unroll
            for (int i = 0; i < 8; ++i) acc[j][i] += wv[j] * xv[i];
    }
    unsigned short* outb = out + (size_t)b * (64 * HW);
#pragma unroll
    for (int j = 0; j < 8; ++j)
#pragma unroll
        for (int i = 0; i < 8; ++i)
            outb[(ty * 8 + j) * HW + hw0 + i * 32] = f2bf(acc[j][i]);
}

// MFMA attention. One block (512 thr = 8 waves) per (b,c).
// LDS: bufA (Q then P), bufB (K then Vt), each 128x128 bf16, XOR-chunk swizzle:
// element (row, k) stored at row*128 + ((k>>3) ^ (row&7))*8 + (k&7).
// Frag reads (A and B patterns) are then conflict-free ds_read_b128.
__global__ __launch_bounds__(512, 4)
void attn_kernel(const unsigned short* __restrict__ Q, const unsigned short* __restrict__ K,
                 const unsigned short* __restrict__ V, float* __restrict__ io,
                 float* __restrict__ stats, int accumulate) {
    __shared__ short bufA[16384];  // 32 KB
    __shared__ short bufB[16384];  // 32 KB
    int bc = blockIdx.x;
    size_t base = (size_t)bc * HW;
    int tid = threadIdx.x;
    int lane = tid & 63;
    int wv = tid >> 6;         // wave -> row strip [16wv, 16wv+16)
    int quad = lane >> 4;
    int m16 = lane & 15;

    // ---- Preload V into registers (overlaps with QK^T latency) ----
    uint4 vreg[4];
    {
        int g0 = tid >> 4;          // 0..31
        int w0 = (tid & 15) * 8;
#pragma unroll
        for (int i = 0; i < 4; ++i)
            vreg[i] = *(const uint4*)(V + base + (size_t)(g0 + 32 * i) * 128 + w0);
    }

    // ---- Stage Q -> bufA, K -> bufB (swizzled) ----
    {
        int r0 = tid >> 4;          // 0..31
        int c0 = tid & 15;          // chunk
#pragma unroll
        for (int i = 0; i < 4; ++i) {
            int r = r0 + 32 * i;
            uint4 q = *(const uint4*)(Q + base + (size_t)r * 128 + c0 * 8);
            uint4 k = *(const uint4*)(K + base + (size_t)r * 128 + c0 * 8);
            int ch = c0 ^ (r & 7);
            *reinterpret_cast<uint4*>(&bufA[r * 128 + ch * 8]) = q;
            *reinterpret_cast<uint4*>(&bufB[r * 128 + ch * 8]) = k;
        }
    }
    __syncthreads();

    // ---- S = Q K^T : A-frags from bufA (own strip), B-frags from bufB ----
    int rowA = wv * 16 + m16;
    int sw = m16 & 7;  // rowA&7 == (16n+m16)&7 == m16&7 for all tiles
    bf16x8 aF[4];
#pragma unroll
    for (int ks = 0; ks < 4; ++ks) {
        int ch = (ks * 4 + quad) ^ sw;
        aF[ks] = *reinterpret_cast<const bf16x8*>(&bufA[rowA * 128 + ch * 8]);
    }
    f32x4 sacc[8];
#pragma unroll
    for (int n = 0; n < 8; ++n) {
        f32x4 acc = {0.f, 0.f, 0.f, 0.f};
        int rowB = n * 16 + m16;
#pragma unroll
        for (int ks = 0; ks < 4; ++ks) {
            int ch = (ks * 4 + quad) ^ sw;
            bf16x8 bF = *reinterpret_cast<const bf16x8*>(&bufB[rowB * 128 + ch * 8]);
            acc = __builtin_amdgcn_mfma_f32_16x16x32_bf16(aF[ks], bF, acc, 0, 0, 0);
        }
        sacc[n] = acc;
    }

    // ---- softmax over g (cols), rows live in regs: row = 16wv + quad*4 + r ----
    const float scale = 0.08838834764831845f;  // 1/sqrt(128)
    float mx[4] = {-3.4e38f, -3.4e38f, -3.4e38f, -3.4e38f};
#pragma unroll
    for (int n = 0; n < 8; ++n)
#pragma unroll
        for (int r = 0; r < 4; ++r) {
            sacc[n][r] *= scale;
            mx[r] = fmaxf(mx[r], sacc[n][r]);
        }
#pragma unroll
    for (int mask = 8; mask >= 1; mask >>= 1)
#pragma unroll
        for (int r = 0; r < 4; ++r) mx[r] = fmaxf(mx[r], __shfl_xor(mx[r], mask));
    float sum[4] = {0.f, 0.f, 0.f, 0.f};
#pragma unroll
    for (int n = 0; n < 8; ++n)
#pragma unroll
        for (int r = 0; r < 4; ++r) {
            float e = __expf(sacc[n][r] - mx[r]);
            sacc[n][r] = e;
            sum[r] += e;
        }
#pragma unroll
    for (int mask = 8; mask >= 1; mask >>= 1)
#pragma unroll
        for (int r = 0; r < 4; ++r) sum[r] += __shfl_xor(sum[r], mask);
    float inv[4];
#pragma unroll
    for (int r = 0; r < 4; ++r) inv[r] = 1.0f / sum[r];

    // ---- write P (bf16) into bufA over Q (wave-private strip; no barrier) ----
#pragma unroll
    for (int n = 0; n < 8; ++n)
#pragma unroll
        for (int r = 0; r < 4; ++r) {
            int row = wv * 16 + quad * 4 + r;
            int col = n * 16 + m16;
            int pos = row * 128 + (((col >> 3) ^ (row & 7)) * 8) + (col & 7);
            bufA[pos] = (short)f2bf(sacc[n][r] * inv[r]);
        }

    __syncthreads();  // all K B-frag reads done -> safe to overwrite bufB

    // ---- Vt (transposed, swizzled) into bufB from vreg ----
    {
        int g0 = tid >> 4;
        int w0 = (tid & 15) * 8;
#pragma unroll
        for (int i = 0; i < 4; ++i) {
            int g = g0 + 32 * i;
            unsigned short e[8];
            *(uint4*)e = vreg[i];
#pragma unroll
            for (int jj = 0; jj < 8; ++jj) {
                int j = jj ^ (tid & 7);  // stagger to break bank pile-up
                int w = w0 + j;
                int pos = w * 128 + (((g >> 3) ^ (w & 7)) * 8) + (g & 7);
                bufB[pos] = (short)e[j];
            }
        }
    }
    __syncthreads();

    // ---- O = P V : A-frags = P (bufA own strip), B-frags = Vt (bufB) ----
#pragma unroll
    for (int ks = 0; ks < 4; ++ks) {
        int ch = (ks * 4 + quad) ^ sw;
        aF[ks] = *reinterpret_cast<const bf16x8*>(&bufA[rowA * 128 + ch * 8]);
    }
    f32x4 oacc[8];
#pragma unroll
    for (int n = 0; n < 8; ++n) {
        f32x4 acc = {0.f, 0.f, 0.f, 0.f};
        int rowB = n * 16 + m16;
#pragma unroll
        for (int ks = 0; ks < 4; ++ks) {
            int ch = (ks * 4 + quad) ^ sw;
            bf16x8 bF = *reinterpret_cast<const bf16x8*>(&bufB[rowB * 128 + ch * 8]);
            acc = __builtin_amdgcn_mfma_f32_16x16x32_bf16(aF[ks], bF, acc, 0, 0, 0);
        }
        oacc[n] = acc;
    }

    // ---- epilogue: io (fp32) ; C layout: row = 16wv + quad*4 + r, col = 16n + m16
    if (!accumulate) {
#pragma unroll
        for (int n = 0; n < 8; ++n)
#pragma unroll
            for (int r = 0; r < 4; ++r) {
                int row = wv * 16 + quad * 4 + r;
                int col = n * 16 + m16;
                io[base + row * 128 + col] = oacc[n][r];
            }
    } else {
        float lsum = 0.f, lsq = 0.f;
#pragma unroll
        for (int n = 0; n < 8; ++n)
#pragma unroll
            for (int r = 0; r < 4; ++r) {
                int row = wv * 16 + quad * 4 + r;
                int col = n * 16 + m16;
                size_t idx = base + row * 128 + col;
                float f = io[idx] + oacc[n][r];
                io[idx] = f;
                lsum += f;
                lsq += f * f;
            }
#pragma unroll
        for (int mask = 32; mask >= 1; mask >>= 1) {
            lsum += __shfl_xor(lsum, mask);
            lsq  += __shfl_xor(lsq,  mask);
        }
        if (lane == 0) {
            int c = bc & 63;
            atomicAdd(&stats[c], lsum);
            atomicAdd(&stats[64 + c], lsq);
        }
    }
}

// in-place fp32: io = relu((io - mean) * rsqrt(var+eps) * gamma + beta)
__global__ __launch_bounds__(256)
void bn_relu_kernel(float* __restrict__ io, const float* __restrict__ stats,
                    const float* __restrict__ gamma, const float* __restrict__ beta) {
    int idx = blockIdx.x * 256 + threadIdx.x;
    int e = idx << 2;
    int c = (e >> 14) & 63;
    const float invN = 1.0f / 262144.0f;
    float mean = stats[c] * invN;
    float var = stats[64 + c] * invN - mean * mean;
    float k = rsqrtf(var + 1e-5f) * gamma[c];
    float bb = beta[c] - mean * k;
    float4 f = reinterpret_cast<const float4*>(io)[idx];
    float4 o;
    o.x = fmaxf(f.x * k + bb, 0.f);
    o.y = fmaxf(f.y * k + bb, 0.f);
    o.z = fmaxf(f.z * k + bb, 0.f);
    o.w = fmaxf(f.w * k + bb, 0.f);
    reinterpret_cast<float4*>(io)[idx] = o;
}

extern "C" void kernel_launch(void* const* d_in, const int* in_sizes, int n_in,
                              void* d_out, int out_size, void* d_ws, size_t ws_size,
                              hipStream_t stream) {
    const float* x1 = (const float*)d_in[0];
    const float* x2 = (const float*)d_in[1];
    const float* rssi1 = (const float*)d_in[2];
    const float* rssi2 = (const float*)d_in[3];
    const float* qw = (const float*)d_in[4];
    const float* qb = (const float*)d_in[5];
    const float* kw = (const float*)d_in[6];
    const float* kb = (const float*)d_in[7];
    const float* vw = (const float*)d_in[8];
    const float* vb = (const float*)d_in[9];
    const float* gamma = (const float*)d_in[10];
    const float* beta = (const float*)d_in[11];

    float* stats = (float*)d_ws;
    unsigned short* Q = (unsigned short*)((char*)d_ws + 512);
    unsigned short* K = Q + NE;
    unsigned short* V = K + NE;
    float* io = (float*)d_out;

    zero_stats_kernel<<<1, 128, 0, stream>>>(stats);

    dim3 pb(256), pg(1024);

    // branch 1
    proj_kernel<<<pg, pb, 0, stream>>>(rssi1, qw, qb, Q);
    proj_kernel<<<pg, pb, 0, stream>>>(x1, kw, kb, K);
    proj_kernel<<<pg, pb, 0, stream>>>(x1, vw, vb, V);
    attn_kernel<<<1024, 512, 0, stream>>>(Q, K, V, io, stats, 0);

    // branch 2
    proj_kernel<<<pg, pb, 0, stream>>>(rssi2, qw, qb, Q);
    proj_kernel<<<pg, pb, 0, stream>>>(x2, kw, kb, K);
    proj_kernel<<<pg, pb, 0, stream>>>(x2, vw, vb, V);
    attn_kernel<<<1024, 512, 0, stream>>>(Q, K, V, io, stats, 1);

    bn_relu_kernel<<<16384, 256, 0, stream>>>(io, stats, gamma, beta);
}